// Round 1
// baseline (95.981 us; speedup 1.0000x reference)
//
#include <hip/hip_runtime.h>
#include <math.h>

// Problem constants (fixed by the reference)
#define B_   16
#define F_   32
#define NP_  128   // Np = FNP / F = 4096/32
#define D_   512
#define P_   16
#define S_   8
#define KC   32            // K-chunk in floats (128 B per row per chunk)
#define NCH  (D_ / KC)     // 16 chunks

__global__ __launch_bounds__(256, 2)
void pd_kernel(const float* __restrict__ ts,
               const float* __restrict__ W,
               const float* __restrict__ bias,
               float* __restrict__ out, int T)
{
    // staging: 2 buffers x 128 rows x 32 floats = 32 KB; reused as raw_lds later
    __shared__ float smem[2 * NP_ * KC];

    const int tid  = threadIdx.x;
    const int lane = tid & 63;
    // each wave owns 8 consecutive e's; force SGPR so W loads scalarize
    const int e0   = __builtin_amdgcn_readfirstlane((tid >> 6) << 3);

    const int blk = blockIdx.x;      // = b*32 + f
    const int b   = blk >> 5;
    const int f   = blk & 31;
    const float* __restrict__ tsb = ts + (size_t)blk * NP_ * D_;  // 128 contiguous rows

    float acc[2][8];
#pragma unroll
    for (int j = 0; j < 2; ++j)
#pragma unroll
        for (int eo = 0; eo < 8; ++eo) acc[j][eo] = 0.f;

    // ---- stage chunk 0 into buffer 0 (pre-swizzled global source, linear LDS dest)
    {
#pragma unroll
        for (int it = 0; it < 4; ++it) {
            int slot = it * 256 + tid;           // 0..1023 16B-slots
            int n  = slot >> 3;
            int ql = slot & 7;
            int qg = ql ^ (n & 7);               // XOR quad swizzle
            const float* src = tsb + n * D_ + (qg << 2);
            __builtin_amdgcn_global_load_lds(
                (const __attribute__((address_space(1))) unsigned int*)src,
                (__attribute__((address_space(3))) unsigned int*)&smem[slot << 2],
                16, 0, 0);
        }
    }
    __syncthreads();

    const int sw = lane & 7;

    for (int c = 0; c < NCH; ++c) {
        // ---- stage chunk c+1 into the other buffer (overlaps with compute below)
        if (c + 1 < NCH) {
            const int k0 = (c + 1) * KC;
            float* dstb = smem + ((c + 1) & 1) * (NP_ * KC);
#pragma unroll
            for (int it = 0; it < 4; ++it) {
                int slot = it * 256 + tid;
                int n  = slot >> 3;
                int ql = slot & 7;
                int qg = ql ^ (n & 7);
                const float* src = tsb + n * D_ + k0 + (qg << 2);
                __builtin_amdgcn_global_load_lds(
                    (const __attribute__((address_space(1))) unsigned int*)src,
                    (__attribute__((address_space(3))) unsigned int*)&dstb[slot << 2],
                    16, 0, 0);
            }
        }

        // ---- compute on current buffer
        const float* buf = smem + (c & 1) * (NP_ * KC);
        const int kb = c * KC;
#pragma unroll
        for (int q = 0; q < 8; ++q) {
            // swizzled read: fetch GLOBAL quad q for this lane's rows
            const float4 a0 = *(const float4*)(buf + lane        * KC + ((q ^ sw) << 2));
            const float4 a1 = *(const float4*)(buf + (lane + 64) * KC + ((q ^ sw) << 2));
            const float* wq = W + kb + (q << 2);   // wave-uniform -> s_load
#pragma unroll
            for (int eo = 0; eo < 8; ++eo) {
                const float* we = wq + (e0 + eo) * D_;
                const float w0 = we[0], w1 = we[1], w2 = we[2], w3 = we[3];
                acc[0][eo] += a0.x * w0 + a0.y * w1 + a0.z * w2 + a0.w * w3;
                acc[1][eo] += a1.x * w0 + a1.y * w1 + a1.z * w2 + a1.w * w3;
            }
        }
        __syncthreads();   // drains stage(c+1) (vmcnt) + all ds_reads of buf (lgkm)
    }

    // ---- epilogue: raw -> LDS (padded stride 33, conflict-free), then gather
#pragma unroll
    for (int j = 0; j < 2; ++j) {
        const int n = lane + (j << 6);
#pragma unroll
        for (int eo = 0; eo < 8; ++eo) {
            const int e = e0 + eo;
            float v = acc[j][eo] + bias[e];
            if (e >= P_) v = fmaxf(expf(v), 1e-6f);   // sigma half
            smem[n * 33 + e] = v;
        }
    }
    __syncthreads();

    // out[b, t, f] = sum_{n: p=t-8n in [0,16)} raw[n][p (+16)] / count(t)
    const int TF = T * F_;
    const size_t halfoff = (size_t)B_ * TF;
    for (int item = tid; item < 2 * T; item += 256) {
        const int half = (item >= T) ? 1 : 0;
        const int t    = item - half * T;
        const int nmax = min(NP_ - 1, t >> 3);
        const int nmin = (t > 8) ? ((t - 8) >> 3) : 0;
        float sum = 0.f;
        const int cnt = nmax - nmin + 1;
        for (int n = nmin; n <= nmax; ++n)
            sum += smem[n * 33 + (half << 4) + (t - (n << 3))];
        const float r = (cnt > 0) ? sum / (float)cnt : 0.f;
        out[(size_t)half * halfoff + (size_t)b * TF + (size_t)t * F_ + f] = r;
    }
}

extern "C" void kernel_launch(void* const* d_in, const int* in_sizes, int n_in,
                              void* d_out, int out_size, void* d_ws, size_t ws_size,
                              hipStream_t stream)
{
    const float* ts   = (const float*)d_in[0];
    const float* W    = (const float*)d_in[1];
    const float* bias = (const float*)d_in[2];
    float* out = (float*)d_out;

    // T derived on host from out_size = 2 * B * T * F
    const int T = out_size / (2 * B_ * F_);

    dim3 grid(B_ * F_);   // 512 blocks, one per (b, f)
    dim3 block(256);
    pd_kernel<<<grid, block, 0, stream>>>(ts, W, bias, out, T);
}

// Round 2
// 51.859 us; speedup vs baseline: 1.8508x; 1.8508x over previous
//
#include <hip/hip_runtime.h>
#include <math.h>

// Problem constants (fixed by the reference)
#define B_   16
#define F_   32
#define NP_  128   // Np = FNP / F = 4096/32
#define D_   512
#define P_   16
#define KC   64            // K-chunk in floats (256 B per row per chunk)
#define NCH  (D_ / KC)     // 8 chunks

__global__ __launch_bounds__(512, 4)
void pd_kernel(const float* __restrict__ ts,
               const float* __restrict__ W,
               const float* __restrict__ bias,
               float* __restrict__ out, int T)
{
    // staging: 2 buffers x 128 rows x 64 floats = 64 KB; reused as raw_lds later
    __shared__ float smem[2 * NP_ * KC];

    const int tid  = threadIdx.x;
    const int lane = tid & 63;
    // 8 waves, each owns 4 consecutive e's; force SGPR so W/bias loads scalarize
    const int e0   = __builtin_amdgcn_readfirstlane((tid >> 6) << 2);

    // XCD-aware block-id encoding: d = (b&7) + 8*(f + 32*(b>>3))
    // => all 32 f's of one b land on the same XCD (round-robin d%8) so the
    //    strided f-column output stores merge in that XCD's L2.
    const int d = blockIdx.x;
    const int b = (d & 7) | ((d >> 8) << 3);
    const int f = (d >> 3) & 31;
    const float* __restrict__ tsb = ts + ((size_t)b * F_ + f) * NP_ * D_;

    float acc[2][4];
#pragma unroll
    for (int j = 0; j < 2; ++j)
#pragma unroll
        for (int eo = 0; eo < 4; ++eo) acc[j][eo] = 0.f;

    // ---- stage chunk 0 into buffer 0 (pre-swizzled global source, linear LDS dest)
#pragma unroll
    for (int it = 0; it < 4; ++it) {
        int slot = it * 512 + tid;           // 0..2047 16B-slots (128 rows x 16 quads)
        int n  = slot >> 4;
        int ql = slot & 15;
        int qg = ql ^ (n & 7);               // XOR quad swizzle (bijective per row)
        const float* src = tsb + n * D_ + (qg << 2);
        __builtin_amdgcn_global_load_lds(
            (const __attribute__((address_space(1))) unsigned int*)src,
            (__attribute__((address_space(3))) unsigned int*)&smem[slot << 2],
            16, 0, 0);
    }
    __syncthreads();

    const int sw = lane & 7;

    for (int c = 0; c < NCH; ++c) {
        // ---- stage chunk c+1 into the other buffer (overlaps with compute below)
        if (c + 1 < NCH) {
            const int k0 = (c + 1) * KC;
            float* dstb = smem + ((c + 1) & 1) * (NP_ * KC);
#pragma unroll
            for (int it = 0; it < 4; ++it) {
                int slot = it * 512 + tid;
                int n  = slot >> 4;
                int ql = slot & 15;
                int qg = ql ^ (n & 7);
                const float* src = tsb + n * D_ + k0 + (qg << 2);
                __builtin_amdgcn_global_load_lds(
                    (const __attribute__((address_space(1))) unsigned int*)src,
                    (__attribute__((address_space(3))) unsigned int*)&dstb[slot << 2],
                    16, 0, 0);
            }
        }

        // ---- compute on current buffer
        const float* buf  = smem + (c & 1) * (NP_ * KC);
        const float* row0 = buf + lane * KC;
        const float* row1 = row0 + 64 * KC;
        const int kb = c * KC;
#pragma unroll
        for (int q = 0; q < 16; ++q) {
            // swizzled read: global quad q lives at LDS quad q^(row&7)
            const int off = ((q ^ sw) << 2);
            const float4 a0 = *(const float4*)(row0 + off);
            const float4 a1 = *(const float4*)(row1 + off);
            const float* wq = W + kb + (q << 2);   // wave-uniform -> s_load
#pragma unroll
            for (int eo = 0; eo < 4; ++eo) {
                const float* we = wq + (e0 + eo) * D_;
                const float w0 = we[0], w1 = we[1], w2 = we[2], w3 = we[3];
                acc[0][eo] += a0.x * w0 + a0.y * w1 + a0.z * w2 + a0.w * w3;
                acc[1][eo] += a1.x * w0 + a1.y * w1 + a1.z * w2 + a1.w * w3;
            }
        }
        __syncthreads();   // drains stage(c+1) (vmcnt) + all ds_reads of buf (lgkm)
    }

    // ---- epilogue: raw -> LDS (padded stride 33, conflict-free), then gather
#pragma unroll
    for (int j = 0; j < 2; ++j) {
        const int n = lane + (j << 6);
#pragma unroll
        for (int eo = 0; eo < 4; ++eo) {
            const int e = e0 + eo;
            float v = acc[j][eo] + bias[e];
            if (e >= P_) v = fmaxf(expf(v), 1e-6f);   // sigma half (wave-uniform branch)
            smem[n * 33 + e] = v;
        }
    }
    __syncthreads();

    // out[b, t, f] = sum_{n: p=t-8n in [0,16)} raw[n][p (+16)] / count(t)
    const int TF = T * F_;
    const size_t halfoff = (size_t)B_ * TF;
    for (int item = tid; item < 2 * T; item += 512) {
        const int half = (item >= T) ? 1 : 0;
        const int t    = item - half * T;
        const int nmax = min(NP_ - 1, t >> 3);
        const int nmin = (t > 8) ? ((t - 8) >> 3) : 0;
        float sum = 0.f;
        const int cnt = nmax - nmin + 1;
        for (int n = nmin; n <= nmax; ++n)
            sum += smem[n * 33 + (half << 4) + (t - (n << 3))];
        const float r = (cnt > 0) ? sum / (float)cnt : 0.f;
        out[(size_t)half * halfoff + (size_t)b * TF + (size_t)t * F_ + f] = r;
    }
}

extern "C" void kernel_launch(void* const* d_in, const int* in_sizes, int n_in,
                              void* d_out, int out_size, void* d_ws, size_t ws_size,
                              hipStream_t stream)
{
    const float* ts   = (const float*)d_in[0];
    const float* W    = (const float*)d_in[1];
    const float* bias = (const float*)d_in[2];
    float* out = (float*)d_out;

    // T derived on host from out_size = 2 * B * T * F
    const int T = out_size / (2 * B_ * F_);

    dim3 grid(B_ * F_);   // 512 blocks, one per (b, f), XCD-encoded id
    dim3 block(512);
    pd_kernel<<<grid, block, 0, stream>>>(ts, W, bias, out, T);
}